// Round 2
// baseline (1948.641 us; speedup 1.0000x reference)
//
#include <hip/hip_runtime.h>

#define D 64

// ---------------- CSR build ----------------

__global__ __launch_bounds__(256) void hist_kernel(const int* __restrict__ dst,
                                                   int* __restrict__ cnt, int E) {
  int e = blockIdx.x * 256 + threadIdx.x;
  if (e < E) atomicAdd(&cnt[dst[e]], 1);
}

__global__ __launch_bounds__(1024) void scan_partial_kernel(const int* __restrict__ cnt,
                                                            int* __restrict__ bsum, int N) {
  __shared__ int lds[1024];
  int i = blockIdx.x * 1024 + threadIdx.x;
  lds[threadIdx.x] = (i < N) ? cnt[i] : 0;
  __syncthreads();
  for (int off = 512; off > 0; off >>= 1) {
    if (threadIdx.x < off) lds[threadIdx.x] += lds[threadIdx.x + off];
    __syncthreads();
  }
  if (threadIdx.x == 0) bsum[blockIdx.x] = lds[0];
}

// exclusive scan of up to 64 block sums in one wave
__global__ void scan_bsum_kernel(int* __restrict__ bsum, int nb,
                                 int* __restrict__ row_ptr, int N, int E) {
  int tid = threadIdx.x;  // 64 threads
  int o = (tid < nb) ? bsum[tid] : 0;
  int v = o;
  for (int off = 1; off < 64; off <<= 1) {
    int t = __shfl_up(v, off, 64);
    if (tid >= off) v += t;
  }
  if (tid < nb) bsum[tid] = v - o;       // exclusive
  if (tid == 0) row_ptr[N] = E;          // total is always E
}

__global__ __launch_bounds__(1024) void scan_final_kernel(const int* __restrict__ cnt,
                                                          const int* __restrict__ bsum,
                                                          int* __restrict__ row_ptr,
                                                          int* __restrict__ cursor, int N) {
  __shared__ int lds[1024];
  int tid = threadIdx.x;
  int i = blockIdx.x * 1024 + tid;
  int v = (i < N) ? cnt[i] : 0;
  lds[tid] = v;
  __syncthreads();
  for (int off = 1; off < 1024; off <<= 1) {
    int t = (tid >= off) ? lds[tid - off] : 0;
    __syncthreads();
    lds[tid] += t;
    __syncthreads();
  }
  if (i < N) {
    int excl = bsum[blockIdx.x] + lds[tid] - v;
    row_ptr[i] = excl;
    cursor[i] = excl;
  }
}

__global__ __launch_bounds__(256) void scatter_kernel(const int* __restrict__ srcs,
                                                      const int* __restrict__ dst,
                                                      int* __restrict__ cursor,
                                                      int* __restrict__ csr_src, int E) {
  int e = blockIdx.x * 256 + threadIdx.x;
  if (e < E) {
    int p = atomicAdd(&cursor[dst[e]], 1);
    csr_src[p] = srcs[e];
  }
}

// ---------------- node MLP: R = relu(hn@Wm1+bm1) (chunk-major), HR = hn@Wr+br ----------------
// hn = sc*h + sh (folded BN of previous layer, computed inline from BN sums; bnS==null -> identity)

__global__ __launch_bounds__(256, 4) void node_mlp_kernel(
    const float* __restrict__ hin, const float* __restrict__ bnS, const float* __restrict__ bnSS,
    const float* __restrict__ gammaL, const float* __restrict__ betaL,
    const float* __restrict__ W1, const float* __restrict__ b1,
    const float* __restrict__ W2, const float* __restrict__ b2,
    float* __restrict__ Rout, float* __restrict__ HRout, int N) {
  __shared__ float2 w12[D * D];       // [k][c] = {W1[k][c], W2[k][c]}
  __shared__ float hrow[32][D];
  const int tid = threadIdx.x;
  for (int i = tid; i < D * D; i += 256) w12[i] = make_float2(W1[i], W2[i]);
  const int c = tid & 63;
  const int w = tid >> 6;
  float sc = 1.f, sh = 0.f;
  if (bnS) {
    float invN = 1.f / (float)N;
    float mu = bnS[c] * invN;
    float var = bnSS[c] * invN - mu * mu;
    float s = gammaL[c] * rsqrtf(var + 1e-5f);
    sc = s;
    sh = betaL[c] - mu * s;
  }
  const float bb1 = b1[c], bb2 = b2[c];
  const size_t chunkBase = (size_t)(c >> 4) * N * 16;
  const int cw = c & 15;
  const int ntiles = (N + 31) >> 5;
  for (int t = blockIdx.x; t < ntiles; t += gridDim.x) {
    const int base = t * 32;
    __syncthreads();
#pragma unroll
    for (int j = 0; j < 8; ++j) {
      int r = (tid + j * 256) >> 6;  // channel == c for all j
      int row = base + r;
      float v = (row < N) ? hin[(size_t)row * D + c] : 0.f;
      hrow[r][c] = v * sc + sh;
    }
    __syncthreads();
    float a1[8], a2[8];
#pragma unroll
    for (int j = 0; j < 8; ++j) { a1[j] = bb1; a2[j] = bb2; }
    for (int k = 0; k < D; k += 4) {
      const float2 wa = w12[(k + 0) * D + c];
      const float2 wb = w12[(k + 1) * D + c];
      const float2 wc = w12[(k + 2) * D + c];
      const float2 wd = w12[(k + 3) * D + c];
#pragma unroll
      for (int j = 0; j < 8; ++j) {
        const float4 h4 = *(const float4*)&hrow[w * 8 + j][k];
        a1[j] += h4.x * wa.x + h4.y * wb.x + h4.z * wc.x + h4.w * wd.x;
        a2[j] += h4.x * wa.y + h4.y * wb.y + h4.z * wc.y + h4.w * wd.y;
      }
    }
#pragma unroll
    for (int j = 0; j < 8; ++j) {
      int row = base + w * 8 + j;
      if (row < N) {
        Rout[chunkBase + (size_t)row * 16 + cw] = fmaxf(a1[j], 0.f);
        HRout[(size_t)row * D + c] = a2[j];
      }
    }
  }
}

// ---------------- chunked gather: agg[n][chunk*16+ch] = sum_e R_chunk[src_e][ch] ----------------

__global__ __launch_bounds__(256) void gather_kernel(const int* __restrict__ row_ptr,
                                                     const int* __restrict__ csr_src,
                                                     const float* __restrict__ Rc,
                                                     float* __restrict__ aggbuf,
                                                     int N, int nbpc) {
  const int chunk = blockIdx.x / nbpc;
  const int nb = blockIdx.x % nbpc;
  const int lane = threadIdx.x & 63;
  const int wv = threadIdx.x >> 6;
  const int g = lane >> 4;
  const int ch = lane & 15;
  const int n = nb * 4 + wv;
  if (n >= N) return;
  const int e0 = row_ptr[n];
  const int e1 = row_ptr[n + 1];
  const float* __restrict__ R = Rc + (size_t)chunk * N * 16;
  float acc = 0.f;
  for (int k = e0 + g; k < e1; k += 4) {
    int s = csr_src[k];
    acc += R[(size_t)s * 16 + ch];
  }
  acc += __shfl_xor(acc, 16, 64);
  acc += __shfl_xor(acc, 32, 64);
  if (g == 0) aggbuf[(size_t)n * D + chunk * 16 + ch] = acc;
}

// ---------------- finish: h = PReLU(agg@Wm2 + deg*b2 + HR), BN partial sums ----------------

__global__ __launch_bounds__(256, 4) void finish_kernel(
    const int* __restrict__ row_ptr, const float* __restrict__ aggbuf,
    const float* __restrict__ HR, const float* __restrict__ W2m,
    const float* __restrict__ b2m, const float* __restrict__ aconv,
    float* __restrict__ hout, float* __restrict__ bnsum, float* __restrict__ bnsumsq, int N) {
  __shared__ float2 w2p[(D / 2) * D];  // [k2][c] = {W2[2k2][c], W2[2k2+1][c]}
  __shared__ float arow[32][D];
  __shared__ float red[8][D];
  const int tid = threadIdx.x;
  for (int i = tid; i < (D / 2) * D; i += 256) {
    int k2 = i >> 6, cc = i & 63;
    w2p[i] = make_float2(W2m[(2 * k2) * D + cc], W2m[(2 * k2 + 1) * D + cc]);
  }
  const int c = tid & 63;
  const int w = tid >> 6;
  const float alpha = *aconv;
  const float bb = b2m[c];
  float psum = 0.f, psumsq = 0.f;
  const int ntiles = (N + 31) >> 5;
  for (int t = blockIdx.x; t < ntiles; t += gridDim.x) {
    const int base = t * 32;
    __syncthreads();
#pragma unroll
    for (int j = 0; j < 8; ++j) {
      int r = (tid + j * 256) >> 6;
      int row = base + r;
      arow[r][c] = (row < N) ? aggbuf[(size_t)row * D + c] : 0.f;
    }
    __syncthreads();
    float a[8];
#pragma unroll
    for (int j = 0; j < 8; ++j) a[j] = 0.f;
    for (int k2 = 0; k2 < D / 2; k2 += 2) {
      const float2 wa = w2p[k2 * D + c];
      const float2 wb = w2p[(k2 + 1) * D + c];
#pragma unroll
      for (int j = 0; j < 8; ++j) {
        const float4 h4 = *(const float4*)&arow[w * 8 + j][k2 * 2];
        a[j] += h4.x * wa.x + h4.y * wa.y + h4.z * wb.x + h4.w * wb.y;
      }
    }
#pragma unroll
    for (int j = 0; j < 8; ++j) {
      int row = base + w * 8 + j;
      if (row < N) {
        float deg = (float)(row_ptr[row + 1] - row_ptr[row]);
        float o = a[j] + bb * deg + HR[(size_t)row * D + c];
        float h2 = (o >= 0.f) ? o : alpha * o;
        hout[(size_t)row * D + c] = h2;
        psum += h2;
        psumsq += h2 * h2;
      }
    }
  }
  red[w][c] = psum;
  red[4 + w][c] = psumsq;
  __syncthreads();
  if (w == 0) {
    float s = red[0][c] + red[1][c] + red[2][c] + red[3][c];
    float ss = red[4][c] + red[5][c] + red[6][c] + red[7][c];
    atomicAdd(&bnsum[c], s);
    atomicAdd(&bnsumsq[c], ss);
  }
}

// ---------------- pooling (sorted batch, binary search) + MLP head ----------------

__global__ __launch_bounds__(256) void pool_head_kernel(
    const float* __restrict__ h, const float* __restrict__ bnS, const float* __restrict__ bnSS,
    const float* __restrict__ gammaL, const float* __restrict__ betaL,
    const int* __restrict__ batch, const float* __restrict__ Wh1, const float* __restrict__ bh1,
    const float* __restrict__ Wh2, const float* __restrict__ bh2,
    const float* __restrict__ ahead, float* __restrict__ out, int N) {
  const int g = blockIdx.x;
  const int tid = threadIdx.x;
  const int c = tid & 63;
  const int w = tid >> 6;
  float sc, sh;
  {
    float invN = 1.f / (float)N;
    float mu = bnS[c] * invN;
    float var = bnSS[c] * invN - mu * mu;
    float s = gammaL[c] * rsqrtf(var + 1e-5f);
    sc = s;
    sh = betaL[c] - mu * s;
  }
  int s0, s1;
  {
    int lo = 0, hi = N;
    while (lo < hi) { int mid = (lo + hi) >> 1; if (batch[mid] < g) lo = mid + 1; else hi = mid; }
    s0 = lo;
    lo = s0; hi = N;
    while (lo < hi) { int mid = (lo + hi) >> 1; if (batch[mid] < g + 1) lo = mid + 1; else hi = mid; }
    s1 = lo;
  }
  float sum = 0.f;
  for (int r = s0 + w; r < s1; r += 4) sum += h[(size_t)r * D + c] * sc + sh;
  __shared__ float red[4][D];
  __shared__ float mean[D];
  red[w][c] = sum;
  __syncthreads();
  if (tid < D) {
    float cnt = (float)(s1 - s0);
    mean[c] = (red[0][c] + red[1][c] + red[2][c] + red[3][c]) / fmaxf(cnt, 1.0f);
  }
  __syncthreads();
  if (tid < D) {
    int j = tid;
    float a = bh1[j];
#pragma unroll
    for (int k = 0; k < D; ++k) a += mean[k] * Wh1[k * D + j];
    float al = *ahead;
    float v = (a >= 0.f) ? a : al * a;
    float pval = v * Wh2[j];
    for (int off = 32; off > 0; off >>= 1) pval += __shfl_down(pval, off, 64);
    if (j == 0) out[g] = pval + bh2[0];
  }
}

// ---------------- host ----------------

extern "C" void kernel_launch(void* const* d_in, const int* in_sizes, int n_in,
                              void* d_out, int out_size, void* d_ws, size_t ws_size,
                              hipStream_t stream) {
  const float* x = (const float*)d_in[0];
  const int* ei = (const int*)d_in[1];
  const int* batch = (const int*)d_in[2];
  const float* Wm1 = (const float*)d_in[3];
  const float* bm1 = (const float*)d_in[4];
  const float* Wm2 = (const float*)d_in[5];
  const float* bm2 = (const float*)d_in[6];
  const float* Wr = (const float*)d_in[7];
  const float* br = (const float*)d_in[8];
  const float* aconv = (const float*)d_in[9];
  const float* gamma = (const float*)d_in[10];
  const float* beta = (const float*)d_in[11];
  const float* Wh1 = (const float*)d_in[12];
  const float* bh1 = (const float*)d_in[13];
  const float* Wh2 = (const float*)d_in[14];
  const float* bh2 = (const float*)d_in[15];
  const float* ahead = (const float*)d_in[16];

  const int N = in_sizes[0] / D;
  const int E = in_sizes[1] / 2;
  const int L = in_sizes[3] / (D * D);
  const int G = out_size;

  const int* srcs = ei;
  const int* dsts = ei + E;

  char* p = (char*)d_ws;
  auto alloc = [&](size_t bytes) {
    char* r = p;
    p += (bytes + 255) & ~(size_t)255;
    return r;
  };
  int* row_ptr = (int*)alloc((size_t)(N + 1) * 4);
  int* cursor = (int*)alloc((size_t)N * 4);
  int* bsum = (int*)alloc(64 * 4);
  int* csr_src = (int*)alloc((size_t)E * 4);
  float* Rbuf = (float*)alloc((size_t)N * D * 4);   // chunk-major [4][N][16]
  float* HRbuf = (float*)alloc((size_t)N * D * 4);
  float* aggbuf = (float*)alloc((size_t)N * D * 4);
  float* hbuf = (float*)alloc((size_t)N * D * 4);
  float* bnsum = (float*)alloc((size_t)L * D * 4 * 2);
  float* bnsumsq = bnsum + (size_t)L * D;

  hipMemsetAsync(row_ptr, 0, (size_t)((char*)(cursor + N) - (char*)row_ptr), stream);
  hipMemsetAsync(bnsum, 0, (size_t)L * D * 4 * 2, stream);

  // CSR build
  const int nb = (N + 1023) / 1024;
  hist_kernel<<<(E + 255) / 256, 256, 0, stream>>>(dsts, cursor, E);
  scan_partial_kernel<<<nb, 1024, 0, stream>>>(cursor, bsum, N);
  scan_bsum_kernel<<<1, 64, 0, stream>>>(bsum, nb, row_ptr, N, E);
  scan_final_kernel<<<nb, 1024, 0, stream>>>(cursor, bsum, row_ptr, cursor, N);
  scatter_kernel<<<(E + 255) / 256, 256, 0, stream>>>(srcs, dsts, cursor, csr_src, E);

  const int ntiles = (N + 31) / 32;
  const int nbpc = (N + 3) / 4;

  const float* hin = x;
  const float* bnS = nullptr;
  const float* bnSS = nullptr;
  const float* gmL = nullptr;
  const float* btL = nullptr;
  for (int l = 0; l < L; ++l) {
    node_mlp_kernel<<<ntiles, 256, 0, stream>>>(hin, bnS, bnSS, gmL, btL,
                                                Wm1 + (size_t)l * D * D, bm1 + l * D,
                                                Wr + (size_t)l * D * D, br + l * D,
                                                Rbuf, HRbuf, N);
    gather_kernel<<<4 * nbpc, 256, 0, stream>>>(row_ptr, csr_src, Rbuf, aggbuf, N, nbpc);
    finish_kernel<<<ntiles, 256, 0, stream>>>(row_ptr, aggbuf, HRbuf,
                                              Wm2 + (size_t)l * D * D, bm2 + l * D, aconv + l,
                                              hbuf, bnsum + l * D, bnsumsq + l * D, N);
    hin = hbuf;
    bnS = bnsum + l * D;
    bnSS = bnsumsq + l * D;
    gmL = gamma + l * D;
    btL = beta + l * D;
  }

  pool_head_kernel<<<G, 256, 0, stream>>>(hbuf, bnS, bnSS, gmL, btL, batch,
                                          Wh1, bh1, Wh2, bh2, ahead, (float*)d_out, N);
}

// Round 3
// 684.649 us; speedup vs baseline: 2.8462x; 2.8462x over previous
//
#include <hip/hip_runtime.h>

#define D 64

// ---------------- CSR build ----------------

__global__ __launch_bounds__(256) void hist_kernel(const int* __restrict__ dst,
                                                   int* __restrict__ cnt, int E) {
  int e = blockIdx.x * 256 + threadIdx.x;
  if (e < E) atomicAdd(&cnt[dst[e]], 1);
}

__global__ __launch_bounds__(1024) void scan_partial_kernel(const int* __restrict__ cnt,
                                                            int* __restrict__ bsum, int N) {
  __shared__ int lds[1024];
  int i = blockIdx.x * 1024 + threadIdx.x;
  lds[threadIdx.x] = (i < N) ? cnt[i] : 0;
  __syncthreads();
  for (int off = 512; off > 0; off >>= 1) {
    if (threadIdx.x < off) lds[threadIdx.x] += lds[threadIdx.x + off];
    __syncthreads();
  }
  if (threadIdx.x == 0) bsum[blockIdx.x] = lds[0];
}

// exclusive scan of up to 64 block sums in one wave
__global__ void scan_bsum_kernel(int* __restrict__ bsum, int nb,
                                 int* __restrict__ row_ptr, int N, int E) {
  int tid = threadIdx.x;  // 64 threads
  int o = (tid < nb) ? bsum[tid] : 0;
  int v = o;
  for (int off = 1; off < 64; off <<= 1) {
    int t = __shfl_up(v, off, 64);
    if (tid >= off) v += t;
  }
  if (tid < nb) bsum[tid] = v - o;       // exclusive
  if (tid == 0) row_ptr[N] = E;          // total is always E
}

__global__ __launch_bounds__(1024) void scan_final_kernel(const int* __restrict__ cnt,
                                                          const int* __restrict__ bsum,
                                                          int* __restrict__ row_ptr,
                                                          int* __restrict__ cursor, int N) {
  __shared__ int lds[1024];
  int tid = threadIdx.x;
  int i = blockIdx.x * 1024 + tid;
  int v = (i < N) ? cnt[i] : 0;
  lds[tid] = v;
  __syncthreads();
  for (int off = 1; off < 1024; off <<= 1) {
    int t = (tid >= off) ? lds[tid - off] : 0;
    __syncthreads();
    lds[tid] += t;
    __syncthreads();
  }
  if (i < N) {
    int excl = bsum[blockIdx.x] + lds[tid] - v;
    row_ptr[i] = excl;
    cursor[i] = excl;
  }
}

__global__ __launch_bounds__(256) void scatter_kernel(const int* __restrict__ srcs,
                                                      const int* __restrict__ dst,
                                                      int* __restrict__ cursor,
                                                      int* __restrict__ csr_src, int E) {
  int e = blockIdx.x * 256 + threadIdx.x;
  if (e < E) {
    int p = atomicAdd(&cursor[dst[e]], 1);
    csr_src[p] = srcs[e];
  }
}

// ---------------- per-layer node MLP: R = relu(h@Wm1+bm1), HR = h@Wr+br ----------------
// applies previous layer's folded BN (h*scale+shift) on load; scale may be null (layer 0)

__global__ __launch_bounds__(256) void node_mlp_kernel(const float* __restrict__ hin,
                                                       const float* __restrict__ scale,
                                                       const float* __restrict__ shift,
                                                       const float* __restrict__ W1,
                                                       const float* __restrict__ b1,
                                                       const float* __restrict__ W2,
                                                       const float* __restrict__ b2,
                                                       float* __restrict__ Rout,
                                                       float* __restrict__ HRout, int N) {
  __shared__ float w1[D * D];
  __shared__ float w2[D * D];
  __shared__ float hrow[16][D];
  const int tid = threadIdx.x;
  for (int i = tid; i < D * D; i += 256) { w1[i] = W1[i]; w2[i] = W2[i]; }
  const int c = tid & 63;
  const int w = tid >> 6;  // 0..3
  const float sc = scale ? scale[c] : 1.0f;
  const float sh = shift ? shift[c] : 0.0f;
  const float bb1 = b1[c], bb2 = b2[c];
  const int ntiles = (N + 15) / 16;
  for (int tile = blockIdx.x; tile < ntiles; tile += gridDim.x) {
    const int base = tile * 16;
    __syncthreads();  // covers weight load on first iter, hrow reuse after
    for (int rr = w; rr < 16; rr += 4) {
      int row = base + rr;
      float v = (row < N) ? hin[row * D + c] : 0.0f;
      hrow[rr][c] = v * sc + sh;
    }
    __syncthreads();
    for (int rr = w; rr < 16; rr += 4) {
      int row = base + rr;
      if (row >= N) break;
      float a1 = bb1, a2 = bb2;
#pragma unroll
      for (int k = 0; k < D; ++k) {
        float v = hrow[rr][k];
        a1 += v * w1[k * D + c];
        a2 += v * w2[k * D + c];
      }
      Rout[row * D + c] = fmaxf(a1, 0.0f);
      HRout[row * D + c] = a2;
    }
  }
}

// ---------------- aggregation + Wm2 + root add + PReLU + BN partial sums ----------------
// edge loop unrolled x4 with independent accumulators: 4 gather loads in flight per wave
// (round-1 profile: 174us, 576 GB/s, VALUBusy 9.7% -> latency-bound serial chain)

__global__ __launch_bounds__(256) void agg_kernel(const int* __restrict__ row_ptr,
                                                  const int* __restrict__ csr_src,
                                                  const float* __restrict__ Rm,
                                                  const float* __restrict__ HRm,
                                                  const float* __restrict__ W2m,
                                                  const float* __restrict__ b2m,
                                                  const float* __restrict__ aconv,
                                                  float* __restrict__ hout,
                                                  float* __restrict__ bnsum,
                                                  float* __restrict__ bnsumsq, int N) {
  __shared__ float w2[D * D];
  __shared__ float aggl[4][D];
  __shared__ float red[4][D];
  __shared__ float red2[4][D];
  const int tid = threadIdx.x;
  const int c = tid & 63;
  const int w = tid >> 6;
  for (int i = tid; i < D * D; i += 256) w2[i] = W2m[i];
  const float alpha = *aconv;
  const float bb = b2m[c];
  float psum = 0.f, psumsq = 0.f;
  __syncthreads();
  for (int n0 = blockIdx.x * 4; n0 < N; n0 += gridDim.x * 4) {
    const int n = n0 + w;
    float acc0 = 0.f, acc1 = 0.f, acc2 = 0.f, acc3 = 0.f;
    int e0 = 0, e1 = 0;
    if (n < N) { e0 = row_ptr[n]; e1 = row_ptr[n + 1]; }
    int k = e0;
    for (; k + 3 < e1; k += 4) {
      const int s0 = csr_src[k];
      const int s1 = csr_src[k + 1];
      const int s2 = csr_src[k + 2];
      const int s3 = csr_src[k + 3];
      acc0 += Rm[(size_t)s0 * D + c];
      acc1 += Rm[(size_t)s1 * D + c];
      acc2 += Rm[(size_t)s2 * D + c];
      acc3 += Rm[(size_t)s3 * D + c];
    }
    for (; k < e1; ++k) acc0 += Rm[(size_t)csr_src[k] * D + c];
    aggl[w][c] = (acc0 + acc1) + (acc2 + acc3);
    __syncthreads();
    if (n < N) {
      float deg = (float)(e1 - e0);
      float o = bb * deg + HRm[n * D + c];
#pragma unroll
      for (int kk = 0; kk < D; ++kk) o += aggl[w][kk] * w2[kk * D + c];
      float h2 = (o >= 0.f) ? o : alpha * o;
      hout[n * D + c] = h2;
      psum += h2;
      psumsq += h2 * h2;
    }
    __syncthreads();
  }
  red[w][c] = psum;
  red2[w][c] = psumsq;
  __syncthreads();
  if (w == 0) {
    float s = red[0][c] + red[1][c] + red[2][c] + red[3][c];
    float ss = red2[0][c] + red2[1][c] + red2[2][c] + red2[3][c];
    atomicAdd(&bnsum[c], s);
    atomicAdd(&bnsumsq[c], ss);
  }
}

// ---------------- BN finalize: fold into scale/shift ----------------

__global__ void bnfin_kernel(const float* __restrict__ bsumv, const float* __restrict__ bsumsq,
                             const float* __restrict__ gamma_l, const float* __restrict__ beta_l,
                             float* __restrict__ scalev, float* __restrict__ shiftv, int N) {
  int c = threadIdx.x;
  float invN = 1.0f / (float)N;
  float mu = bsumv[c] * invN;
  float var = bsumsq[c] * invN - mu * mu;
  float rs = rsqrtf(var + 1e-5f);
  float s = gamma_l[c] * rs;
  scalev[c] = s;
  shiftv[c] = beta_l[c] - mu * s;
}

// ---------------- pooling (sorted batch, binary search) + MLP head ----------------

__global__ __launch_bounds__(256) void pool_head_kernel(const float* __restrict__ h,
                                                        const float* __restrict__ scale,
                                                        const float* __restrict__ shift,
                                                        const int* __restrict__ batch,
                                                        const float* __restrict__ Wh1,
                                                        const float* __restrict__ bh1,
                                                        const float* __restrict__ Wh2,
                                                        const float* __restrict__ bh2,
                                                        const float* __restrict__ ahead,
                                                        float* __restrict__ out, int N) {
  const int g = blockIdx.x;
  const int tid = threadIdx.x;
  const int c = tid & 63;
  const int w = tid >> 6;
  // lower_bound(batch, g) and lower_bound(batch, g+1)
  int s0, s1;
  {
    int lo = 0, hi = N;
    while (lo < hi) { int mid = (lo + hi) >> 1; if (batch[mid] < g) lo = mid + 1; else hi = mid; }
    s0 = lo;
    lo = s0; hi = N;
    while (lo < hi) { int mid = (lo + hi) >> 1; if (batch[mid] < g + 1) lo = mid + 1; else hi = mid; }
    s1 = lo;
  }
  const float sc = scale[c], sh = shift[c];
  float sum = 0.f;
  for (int r = s0 + w; r < s1; r += 4) sum += h[r * D + c] * sc + sh;
  __shared__ float red[4][D];
  __shared__ float mean[D];
  red[w][c] = sum;
  __syncthreads();
  if (tid < D) {
    float cnt = (float)(s1 - s0);
    mean[c] = (red[0][c] + red[1][c] + red[2][c] + red[3][c]) / fmaxf(cnt, 1.0f);
  }
  __syncthreads();
  if (tid < D) {
    int j = tid;
    float a = bh1[j];
#pragma unroll
    for (int k = 0; k < D; ++k) a += mean[k] * Wh1[k * D + j];
    float al = *ahead;
    float v = (a >= 0.f) ? a : al * a;
    float pval = v * Wh2[j];
    for (int off = 32; off > 0; off >>= 1) pval += __shfl_down(pval, off, 64);
    if (j == 0) out[g] = pval + bh2[0];
  }
}

// ---------------- host ----------------

extern "C" void kernel_launch(void* const* d_in, const int* in_sizes, int n_in,
                              void* d_out, int out_size, void* d_ws, size_t ws_size,
                              hipStream_t stream) {
  const float* x = (const float*)d_in[0];
  const int* ei = (const int*)d_in[1];
  const int* batch = (const int*)d_in[2];
  const float* Wm1 = (const float*)d_in[3];
  const float* bm1 = (const float*)d_in[4];
  const float* Wm2 = (const float*)d_in[5];
  const float* bm2 = (const float*)d_in[6];
  const float* Wr = (const float*)d_in[7];
  const float* br = (const float*)d_in[8];
  const float* aconv = (const float*)d_in[9];
  const float* gamma = (const float*)d_in[10];
  const float* beta = (const float*)d_in[11];
  const float* Wh1 = (const float*)d_in[12];
  const float* bh1 = (const float*)d_in[13];
  const float* Wh2 = (const float*)d_in[14];
  const float* bh2 = (const float*)d_in[15];
  const float* ahead = (const float*)d_in[16];

  const int N = in_sizes[0] / D;
  const int E = in_sizes[1] / 2;
  const int L = in_sizes[3] / (D * D);
  const int G = out_size;

  const int* srcs = ei;
  const int* dsts = ei + E;

  char* p = (char*)d_ws;
  auto alloc = [&](size_t bytes) {
    char* r = p;
    p += (bytes + 255) & ~(size_t)255;
    return r;
  };
  int* row_ptr = (int*)alloc((size_t)(N + 1) * 4);
  int* cursor = (int*)alloc((size_t)N * 4);
  int* bsum = (int*)alloc(64 * 4);
  int* csr_src = (int*)alloc((size_t)E * 4);
  float* Rbuf = (float*)alloc((size_t)N * D * 4);
  float* HRbuf = (float*)alloc((size_t)N * D * 4);
  float* hbuf = (float*)alloc((size_t)N * D * 4);
  float* bnsum = (float*)alloc((size_t)L * D * 4 * 2);  // sums then sumsq, contiguous
  float* bnsumsq = bnsum + (size_t)L * D;
  float* scales = (float*)alloc((size_t)L * D * 4);
  float* shifts = (float*)alloc((size_t)L * D * 4);

  // zero counters (cursor doubles as histogram buffer) and BN accumulators
  hipMemsetAsync(row_ptr, 0, (size_t)((char*)(cursor + N) - (char*)row_ptr), stream);
  hipMemsetAsync(bnsum, 0, (size_t)L * D * 4 * 2, stream);

  // CSR build
  const int nb = (N + 1023) / 1024;
  hist_kernel<<<(E + 255) / 256, 256, 0, stream>>>(dsts, cursor, E);
  scan_partial_kernel<<<nb, 1024, 0, stream>>>(cursor, bsum, N);
  scan_bsum_kernel<<<1, 64, 0, stream>>>(bsum, nb, row_ptr, N, E);
  scan_final_kernel<<<nb, 1024, 0, stream>>>(cursor, bsum, row_ptr, cursor, N);
  scatter_kernel<<<(E + 255) / 256, 256, 0, stream>>>(srcs, dsts, cursor, csr_src, E);

  // layers
  const float* hin = x;
  const float* sc = nullptr;
  const float* sh = nullptr;
  for (int l = 0; l < L; ++l) {
    node_mlp_kernel<<<1024, 256, 0, stream>>>(hin, sc, sh, Wm1 + (size_t)l * D * D, bm1 + l * D,
                                              Wr + (size_t)l * D * D, br + l * D, Rbuf, HRbuf, N);
    agg_kernel<<<2048, 256, 0, stream>>>(row_ptr, csr_src, Rbuf, HRbuf, Wm2 + (size_t)l * D * D,
                                         bm2 + l * D, aconv + l, hbuf, bnsum + l * D,
                                         bnsumsq + l * D, N);
    bnfin_kernel<<<1, 64, 0, stream>>>(bnsum + l * D, bnsumsq + l * D, gamma + l * D, beta + l * D,
                                       scales + l * D, shifts + l * D, N);
    hin = hbuf;
    sc = scales + l * D;
    sh = shifts + l * D;
  }

  pool_head_kernel<<<G, 256, 0, stream>>>(hbuf, sc, sh, batch, Wh1, bh1, Wh2, bh2, ahead,
                                          (float*)d_out, N);
}

// Round 4
// 621.322 us; speedup vs baseline: 3.1363x; 1.1019x over previous
//
#include <hip/hip_runtime.h>

#define D 64

// ---------------- CSR build ----------------

__global__ __launch_bounds__(256) void hist_kernel(const int* __restrict__ dst,
                                                   int* __restrict__ cnt, int E) {
  int e = blockIdx.x * 256 + threadIdx.x;
  if (e < E) atomicAdd(&cnt[dst[e]], 1);
}

__global__ __launch_bounds__(1024) void scan_partial_kernel(const int* __restrict__ cnt,
                                                            int* __restrict__ bsum, int N) {
  __shared__ int lds[1024];
  int i = blockIdx.x * 1024 + threadIdx.x;
  lds[threadIdx.x] = (i < N) ? cnt[i] : 0;
  __syncthreads();
  for (int off = 512; off > 0; off >>= 1) {
    if (threadIdx.x < off) lds[threadIdx.x] += lds[threadIdx.x + off];
    __syncthreads();
  }
  if (threadIdx.x == 0) bsum[blockIdx.x] = lds[0];
}

// exclusive scan of up to 64 block sums in one wave
__global__ void scan_bsum_kernel(int* __restrict__ bsum, int nb,
                                 int* __restrict__ row_ptr, int N, int E) {
  int tid = threadIdx.x;  // 64 threads
  int o = (tid < nb) ? bsum[tid] : 0;
  int v = o;
  for (int off = 1; off < 64; off <<= 1) {
    int t = __shfl_up(v, off, 64);
    if (tid >= off) v += t;
  }
  if (tid < nb) bsum[tid] = v - o;       // exclusive
  if (tid == 0) row_ptr[N] = E;          // total is always E
}

__global__ __launch_bounds__(1024) void scan_final_kernel(const int* __restrict__ cnt,
                                                          const int* __restrict__ bsum,
                                                          int* __restrict__ row_ptr,
                                                          int* __restrict__ cursor, int N) {
  __shared__ int lds[1024];
  int tid = threadIdx.x;
  int i = blockIdx.x * 1024 + tid;
  int v = (i < N) ? cnt[i] : 0;
  lds[tid] = v;
  __syncthreads();
  for (int off = 1; off < 1024; off <<= 1) {
    int t = (tid >= off) ? lds[tid - off] : 0;
    __syncthreads();
    lds[tid] += t;
    __syncthreads();
  }
  if (i < N) {
    int excl = bsum[blockIdx.x] + lds[tid] - v;
    row_ptr[i] = excl;
    cursor[i] = excl;
  }
}

__global__ __launch_bounds__(256) void scatter_kernel(const int* __restrict__ srcs,
                                                      const int* __restrict__ dst,
                                                      int* __restrict__ cursor,
                                                      int* __restrict__ csr_src, int E) {
  int e = blockIdx.x * 256 + threadIdx.x;
  if (e < E) {
    int p = atomicAdd(&cursor[dst[e]], 1);
    csr_src[p] = srcs[e];
  }
}

// ---------------- node MLP: R = relu(h@Wm1+bm1), HR = h@Wr+br ----------------
// vectorized: float2-packed weight pairs, float4 broadcast row reads, 8 rows/thread
// applies previous layer's folded BN (h*scale+shift) on load; scale may be null (layer 0)

__global__ __launch_bounds__(256, 4) void node_mlp_kernel(
    const float* __restrict__ hin, const float* __restrict__ scale,
    const float* __restrict__ shift, const float* __restrict__ W1,
    const float* __restrict__ b1, const float* __restrict__ W2,
    const float* __restrict__ b2, float* __restrict__ Rout,
    float* __restrict__ HRout, int N) {
  __shared__ float2 w12[D * D];  // [k][c] = {W1[k][c], W2[k][c]}
  __shared__ float hrow[32][D];
  const int tid = threadIdx.x;
  for (int i = tid; i < D * D; i += 256) w12[i] = make_float2(W1[i], W2[i]);
  const int c = tid & 63;
  const int w = tid >> 6;
  const float sc = scale ? scale[c] : 1.0f;
  const float sh = shift ? shift[c] : 0.0f;
  const float bb1 = b1[c], bb2 = b2[c];
  const int ntiles = (N + 31) >> 5;
  for (int t = blockIdx.x; t < ntiles; t += gridDim.x) {
    const int base = t * 32;
    __syncthreads();  // covers weight load on first iter, hrow reuse after
#pragma unroll
    for (int j = 0; j < 8; ++j) {
      int r = 4 * j + w;
      int row = base + r;
      float v = (row < N) ? hin[(size_t)row * D + c] : 0.f;
      hrow[r][c] = v * sc + sh;
    }
    __syncthreads();
    float a1[8], a2[8];
#pragma unroll
    for (int j = 0; j < 8; ++j) { a1[j] = bb1; a2[j] = bb2; }
    for (int k = 0; k < D; k += 4) {
      const float2 wa = w12[(k + 0) * D + c];
      const float2 wb = w12[(k + 1) * D + c];
      const float2 wc = w12[(k + 2) * D + c];
      const float2 wd = w12[(k + 3) * D + c];
#pragma unroll
      for (int j = 0; j < 8; ++j) {
        const float4 h4 = *(const float4*)&hrow[w * 8 + j][k];
        a1[j] += h4.x * wa.x + h4.y * wb.x + h4.z * wc.x + h4.w * wd.x;
        a2[j] += h4.x * wa.y + h4.y * wb.y + h4.z * wc.y + h4.w * wd.y;
      }
    }
#pragma unroll
    for (int j = 0; j < 8; ++j) {
      int row = base + w * 8 + j;
      if (row < N) {
        Rout[(size_t)row * D + c] = fmaxf(a1[j], 0.f);
        HRout[(size_t)row * D + c] = a2[j];
      }
    }
  }
}

// ---------------- aggregation + Wm2 + root add + PReLU + BN partial sums ----------------
// barrier-free main loop: each wave owns its nodes; agg broadcast via v_readlane
// (lane kk holds channel kk of the aggregate); 8-deep gather MLP

__device__ __forceinline__ float lane_bcast(float v, int lane) {
  return __int_as_float(__builtin_amdgcn_readlane(__float_as_int(v), lane));
}

__global__ __launch_bounds__(256) void agg_kernel(const int* __restrict__ row_ptr,
                                                  const int* __restrict__ csr_src,
                                                  const float* __restrict__ Rm,
                                                  const float* __restrict__ HRm,
                                                  const float* __restrict__ W2m,
                                                  const float* __restrict__ b2m,
                                                  const float* __restrict__ aconv,
                                                  float* __restrict__ hout,
                                                  float* __restrict__ bnsum,
                                                  float* __restrict__ bnsumsq, int N) {
  __shared__ float w2[D * D];
  __shared__ float red[4][D];
  __shared__ float red2[4][D];
  const int tid = threadIdx.x;
  const int c = tid & 63;
  const int w = tid >> 6;
  for (int i = tid; i < D * D; i += 256) w2[i] = W2m[i];
  const float alpha = *aconv;
  const float bb = b2m[c];
  float psum = 0.f, psumsq = 0.f;
  __syncthreads();
  for (int n = blockIdx.x * 4 + w; n < N; n += gridDim.x * 4) {
    const int e0 = row_ptr[n];
    const int e1 = row_ptr[n + 1];
    float acc0 = 0.f, acc1 = 0.f, acc2 = 0.f, acc3 = 0.f;
    float acc4 = 0.f, acc5 = 0.f, acc6 = 0.f, acc7 = 0.f;
    int k = e0;
    for (; k + 7 < e1; k += 8) {
      const int s0 = csr_src[k];
      const int s1 = csr_src[k + 1];
      const int s2 = csr_src[k + 2];
      const int s3 = csr_src[k + 3];
      const int s4 = csr_src[k + 4];
      const int s5 = csr_src[k + 5];
      const int s6 = csr_src[k + 6];
      const int s7 = csr_src[k + 7];
      acc0 += Rm[(size_t)s0 * D + c];
      acc1 += Rm[(size_t)s1 * D + c];
      acc2 += Rm[(size_t)s2 * D + c];
      acc3 += Rm[(size_t)s3 * D + c];
      acc4 += Rm[(size_t)s4 * D + c];
      acc5 += Rm[(size_t)s5 * D + c];
      acc6 += Rm[(size_t)s6 * D + c];
      acc7 += Rm[(size_t)s7 * D + c];
    }
    for (; k + 3 < e1; k += 4) {
      const int s0 = csr_src[k];
      const int s1 = csr_src[k + 1];
      const int s2 = csr_src[k + 2];
      const int s3 = csr_src[k + 3];
      acc0 += Rm[(size_t)s0 * D + c];
      acc1 += Rm[(size_t)s1 * D + c];
      acc2 += Rm[(size_t)s2 * D + c];
      acc3 += Rm[(size_t)s3 * D + c];
    }
    for (; k < e1; ++k) acc0 += Rm[(size_t)csr_src[k] * D + c];
    const float aggv = ((acc0 + acc1) + (acc2 + acc3)) + ((acc4 + acc5) + (acc6 + acc7));
    const float deg = (float)(e1 - e0);
    float o0 = bb * deg + HRm[(size_t)n * D + c];
    float o1 = 0.f, o2 = 0.f, o3 = 0.f;
#pragma unroll
    for (int kk = 0; kk < D; kk += 4) {
      o0 += lane_bcast(aggv, kk + 0) * w2[(kk + 0) * D + c];
      o1 += lane_bcast(aggv, kk + 1) * w2[(kk + 1) * D + c];
      o2 += lane_bcast(aggv, kk + 2) * w2[(kk + 2) * D + c];
      o3 += lane_bcast(aggv, kk + 3) * w2[(kk + 3) * D + c];
    }
    const float o = (o0 + o1) + (o2 + o3);
    const float h2 = (o >= 0.f) ? o : alpha * o;
    hout[(size_t)n * D + c] = h2;
    psum += h2;
    psumsq += h2 * h2;
  }
  red[w][c] = psum;
  red2[w][c] = psumsq;
  __syncthreads();
  if (w == 0) {
    float s = red[0][c] + red[1][c] + red[2][c] + red[3][c];
    float ss = red2[0][c] + red2[1][c] + red2[2][c] + red2[3][c];
    atomicAdd(&bnsum[c], s);
    atomicAdd(&bnsumsq[c], ss);
  }
}

// ---------------- BN finalize: fold into scale/shift ----------------

__global__ void bnfin_kernel(const float* __restrict__ bsumv, const float* __restrict__ bsumsq,
                             const float* __restrict__ gamma_l, const float* __restrict__ beta_l,
                             float* __restrict__ scalev, float* __restrict__ shiftv, int N) {
  int c = threadIdx.x;
  float invN = 1.0f / (float)N;
  float mu = bsumv[c] * invN;
  float var = bsumsq[c] * invN - mu * mu;
  float rs = rsqrtf(var + 1e-5f);
  float s = gamma_l[c] * rs;
  scalev[c] = s;
  shiftv[c] = beta_l[c] - mu * s;
}

// ---------------- pooling (sorted batch, binary search) + MLP head ----------------

__global__ __launch_bounds__(256) void pool_head_kernel(const float* __restrict__ h,
                                                        const float* __restrict__ scale,
                                                        const float* __restrict__ shift,
                                                        const int* __restrict__ batch,
                                                        const float* __restrict__ Wh1,
                                                        const float* __restrict__ bh1,
                                                        const float* __restrict__ Wh2,
                                                        const float* __restrict__ bh2,
                                                        const float* __restrict__ ahead,
                                                        float* __restrict__ out, int N) {
  const int g = blockIdx.x;
  const int tid = threadIdx.x;
  const int c = tid & 63;
  const int w = tid >> 6;
  // lower_bound(batch, g) and lower_bound(batch, g+1)
  int s0, s1;
  {
    int lo = 0, hi = N;
    while (lo < hi) { int mid = (lo + hi) >> 1; if (batch[mid] < g) lo = mid + 1; else hi = mid; }
    s0 = lo;
    lo = s0; hi = N;
    while (lo < hi) { int mid = (lo + hi) >> 1; if (batch[mid] < g + 1) lo = mid + 1; else hi = mid; }
    s1 = lo;
  }
  const float sc = scale[c], sh = shift[c];
  float sum = 0.f;
  for (int r = s0 + w; r < s1; r += 4) sum += h[r * D + c] * sc + sh;
  __shared__ float red[4][D];
  __shared__ float mean[D];
  red[w][c] = sum;
  __syncthreads();
  if (tid < D) {
    float cnt = (float)(s1 - s0);
    mean[c] = (red[0][c] + red[1][c] + red[2][c] + red[3][c]) / fmaxf(cnt, 1.0f);
  }
  __syncthreads();
  if (tid < D) {
    int j = tid;
    float a = bh1[j];
#pragma unroll
    for (int k = 0; k < D; ++k) a += mean[k] * Wh1[k * D + j];
    float al = *ahead;
    float v = (a >= 0.f) ? a : al * a;
    float pval = v * Wh2[j];
    for (int off = 32; off > 0; off >>= 1) pval += __shfl_down(pval, off, 64);
    if (j == 0) out[g] = pval + bh2[0];
  }
}

// ---------------- host ----------------

extern "C" void kernel_launch(void* const* d_in, const int* in_sizes, int n_in,
                              void* d_out, int out_size, void* d_ws, size_t ws_size,
                              hipStream_t stream) {
  const float* x = (const float*)d_in[0];
  const int* ei = (const int*)d_in[1];
  const int* batch = (const int*)d_in[2];
  const float* Wm1 = (const float*)d_in[3];
  const float* bm1 = (const float*)d_in[4];
  const float* Wm2 = (const float*)d_in[5];
  const float* bm2 = (const float*)d_in[6];
  const float* Wr = (const float*)d_in[7];
  const float* br = (const float*)d_in[8];
  const float* aconv = (const float*)d_in[9];
  const float* gamma = (const float*)d_in[10];
  const float* beta = (const float*)d_in[11];
  const float* Wh1 = (const float*)d_in[12];
  const float* bh1 = (const float*)d_in[13];
  const float* Wh2 = (const float*)d_in[14];
  const float* bh2 = (const float*)d_in[15];
  const float* ahead = (const float*)d_in[16];

  const int N = in_sizes[0] / D;
  const int E = in_sizes[1] / 2;
  const int L = in_sizes[3] / (D * D);
  const int G = out_size;

  const int* srcs = ei;
  const int* dsts = ei + E;

  char* p = (char*)d_ws;
  auto alloc = [&](size_t bytes) {
    char* r = p;
    p += (bytes + 255) & ~(size_t)255;
    return r;
  };
  int* row_ptr = (int*)alloc((size_t)(N + 1) * 4);
  int* cursor = (int*)alloc((size_t)N * 4);
  int* bsum = (int*)alloc(64 * 4);
  int* csr_src = (int*)alloc((size_t)E * 4);
  float* Rbuf = (float*)alloc((size_t)N * D * 4);
  float* HRbuf = (float*)alloc((size_t)N * D * 4);
  float* hbuf = (float*)alloc((size_t)N * D * 4);
  float* bnsum = (float*)alloc((size_t)L * D * 4 * 2);  // sums then sumsq, contiguous
  float* bnsumsq = bnsum + (size_t)L * D;
  float* scales = (float*)alloc((size_t)L * D * 4);
  float* shifts = (float*)alloc((size_t)L * D * 4);

  // zero counters (cursor doubles as histogram buffer) and BN accumulators
  hipMemsetAsync(row_ptr, 0, (size_t)((char*)(cursor + N) - (char*)row_ptr), stream);
  hipMemsetAsync(bnsum, 0, (size_t)L * D * 4 * 2, stream);

  // CSR build
  const int nb = (N + 1023) / 1024;
  hist_kernel<<<(E + 255) / 256, 256, 0, stream>>>(dsts, cursor, E);
  scan_partial_kernel<<<nb, 1024, 0, stream>>>(cursor, bsum, N);
  scan_bsum_kernel<<<1, 64, 0, stream>>>(bsum, nb, row_ptr, N, E);
  scan_final_kernel<<<nb, 1024, 0, stream>>>(cursor, bsum, row_ptr, cursor, N);
  scatter_kernel<<<(E + 255) / 256, 256, 0, stream>>>(srcs, dsts, cursor, csr_src, E);

  const int ntiles = (N + 31) / 32;

  // layers
  const float* hin = x;
  const float* sc = nullptr;
  const float* sh = nullptr;
  for (int l = 0; l < L; ++l) {
    node_mlp_kernel<<<ntiles, 256, 0, stream>>>(hin, sc, sh, Wm1 + (size_t)l * D * D, bm1 + l * D,
                                                Wr + (size_t)l * D * D, br + l * D, Rbuf, HRbuf, N);
    agg_kernel<<<2048, 256, 0, stream>>>(row_ptr, csr_src, Rbuf, HRbuf, Wm2 + (size_t)l * D * D,
                                         bm2 + l * D, aconv + l, hbuf, bnsum + l * D,
                                         bnsumsq + l * D, N);
    bnfin_kernel<<<1, 64, 0, stream>>>(bnsum + l * D, bnsumsq + l * D, gamma + l * D, beta + l * D,
                                       scales + l * D, shifts + l * D, N);
    hin = hbuf;
    sc = scales + l * D;
    sh = shifts + l * D;
  }

  pool_head_kernel<<<G, 256, 0, stream>>>(hbuf, sc, sh, batch, Wh1, bh1, Wh2, bh2, ahead,
                                          (float*)d_out, N);
}